// Round 7
// baseline (98.059 us; speedup 1.0000x reference)
//
#include <hip/hip_runtime.h>

// Fused 3-level B3-spline UWT, fp32. x:(16,1024,1024)->out:(16,4,1024,1024)=[w1,w2,w3,c3].
// No input staging tile: passA reads x straight from global (cache-hot),
// runs the horizontal a-trous cascade h1->h2->h3 in a 48-float register
// buffer, and stores u1(=h1 ctr),u2(=h2 ctr),u3(=h3) to LDS. ONE barrier.
// passB: vertical 5/13/29-tap dense convs from LDS columns (pitch 68 = 4 mod
// 32 -> uniform bank slots, immediate-offset ds_read_b128).
// TB=384: waves 0-3 do w2/w3/c3 (4-row strips), waves 4-5 do w1 (8-row strips).
// 62.7 KB LDS -> 2 blocks/CU (12 waves).

typedef float f4v __attribute__((ext_vector_type(4)));

constexpr int TB   = 384;
constexpr int TCOL = 64;
constexpr int TROW = 64;
constexpr int VH   = 14;         // vertical halo
constexpr int UP   = 68;         // u-tile pitch (floats); 68 % 32 == 4
constexpr int U1R  = 68;         // u1 rows: frame [12,80)
constexpr int U2R  = 76;         // u2 rows: frame [8,84)
constexpr int U3R  = 92;         // u3 rows: frame [0,92)
constexpr int HW   = 1024 * 1024;

__device__ constexpr float K13[13] = {
    1.f/256, 4.f/256, 10.f/256, 20.f/256, 31.f/256, 40.f/256, 44.f/256,
    40.f/256, 31.f/256, 20.f/256, 10.f/256, 4.f/256, 1.f/256};
__device__ constexpr float K29[29] = {
    1.f/4096,   4.f/4096,  10.f/4096,  20.f/4096,  35.f/4096,  56.f/4096,
    84.f/4096, 120.f/4096, 161.f/4096, 204.f/4096, 246.f/4096, 284.f/4096,
    315.f/4096, 336.f/4096, 344.f/4096, 336.f/4096, 315.f/4096, 284.f/4096,
    246.f/4096, 204.f/4096, 161.f/4096, 120.f/4096,  84.f/4096,  56.f/4096,
    35.f/4096,  20.f/4096,  10.f/4096,   4.f/4096,   1.f/4096};

__device__ __forceinline__ int refl(int i) {
    return i < 0 ? -i : (i >= 1024 ? 2046 - i : i);
}

__global__ __launch_bounds__(TB, 3)
void uwt3_kernel(const float* __restrict__ x, float* __restrict__ out)
{
    __shared__ float u1s[U1R * UP];   // 18.1 KB
    __shared__ float u2s[U2R * UP];   // 20.2 KB
    __shared__ float u3s[U3R * UP];   // 24.4 KB

    const int tid = threadIdx.x;

    // bijective XCD chunk swizzle (4096 % 8 == 0)
    const int flat = blockIdx.x;
    const int swz  = (flat & 7) * 512 + (flat >> 3);
    const int bxi = swz & 15;
    const int byi = (swz >> 4) & 15;
    const int bz  = swz >> 8;
    const int bx = bxi * TCOL;
    const int by = byi * TROW;

    const float* xp = x + (size_t)bz * HW;
    float* op = out + (size_t)bz * 4 * HW;

    // ================= passA: horizontal cascade, global -> LDS =============
    // item = (row rp in [0,92), 16-col group gi). F[j] = x[row, bx-16+16gi+j].
    if (tid < 92 * 4) {
        const int gi = tid & 3;
        const int rp = tid >> 2;
        const int gr = refl(by - VH + rp);
        const float* rowp = xp + (size_t)gr * 1024;

        float F[48];
        if (bxi != 0 && bxi != 15) {
            const float* base = rowp + (bx - 16 + 16 * gi);
#pragma unroll
            for (int m = 0; m < 12; ++m)
                *(f4v*)&F[4 * m] = *(const f4v*)(base + 4 * m);
        } else {
#pragma unroll
            for (int c = 0; c < 48; ++c)
                F[c] = rowp[refl(bx - 16 + 16 * gi + c)];
        }

        // stage 1: h1 (d=1); F[i] <- h1 @ x-col (i+2)
#pragma unroll
        for (int i = 2; i < 42; ++i)
            F[i] = 0.0625f * (F[i] + F[i + 4]) + 0.25f * (F[i + 1] + F[i + 3])
                 + 0.375f * F[i + 2];
        // u1 = h1 @ tile cols [16gi,16gi+16) = F[14..30), rows frame [12,80)
        if (rp >= 12 && rp < 80) {
            float* d = u1s + (rp - 12) * UP + 16 * gi;
#pragma unroll
            for (int k = 0; k < 4; ++k) {
                const f4v v = {F[14 + 4*k], F[15 + 4*k], F[16 + 4*k], F[17 + 4*k]};
                *(f4v*)(d + 4 * k) = v;
            }
        }
        // stage 2: h2 (d=2); F[i] <- h2 @ x-col (i+6)
#pragma unroll
        for (int i = 2; i < 34; ++i)
            F[i] = 0.0625f * (F[i] + F[i + 8]) + 0.25f * (F[i + 2] + F[i + 6])
                 + 0.375f * F[i + 4];
        // u2 = h2 @ tile cols = F[10..26), rows frame [8,84)
        if (rp >= 8 && rp < 84) {
            float* d = u2s + (rp - 8) * UP + 16 * gi;
#pragma unroll
            for (int k = 0; k < 4; ++k) {
                const f4v v = {F[10 + 4*k], F[11 + 4*k], F[12 + 4*k], F[13 + 4*k]};
                *(f4v*)(d + 4 * k) = v;
            }
        }
        // stage 3: h3 (d=4); F[i] <- h3 @ x-col (i+14)
#pragma unroll
        for (int i = 2; i < 18; ++i)
            F[i] = 0.0625f * (F[i] + F[i + 16]) + 0.25f * (F[i + 4] + F[i + 12])
                 + 0.375f * F[i + 8];
        // u3 = h3 @ tile cols = F[2..18), all rows
        {
            float* d = u3s + rp * UP + 16 * gi;
#pragma unroll
            for (int k = 0; k < 4; ++k) {
                const f4v v = {F[2 + 4*k], F[3 + 4*k], F[4 + 4*k], F[5 + 4*k]};
                *(f4v*)(d + 4 * k) = v;
            }
        }
    }
    __syncthreads();

    // ================= passB: vertical convs + outputs ======================
    if (tid < 256) {
        // waves 0-3: w2, w3, c3 on 4-row strips
        const int fc = tid & 15;
        const int r0 = (tid >> 4) * 4;
        const size_t gbase = (size_t)(by + r0) * 1024 + bx + 4 * fc;

        // c1 = V1 u1 (5-tap): u1s rows [r0, r0+8)
        f4v u1r[8];
#pragma unroll
        for (int i = 0; i < 8; ++i)
            u1r[i] = *(const f4v*)(u1s + (r0 + i) * UP + 4 * fc);
        f4v c1[4];
#pragma unroll
        for (int j = 0; j < 4; ++j)
            c1[j] = 0.0625f * (u1r[j] + u1r[j + 4]) + 0.25f * (u1r[j + 1] + u1r[j + 3])
                  + 0.375f * u1r[j + 2];

        // c2 = V2 u2 (13-tap): u2s rows [r0, r0+16)
        f4v c2[4] = {{0,0,0,0},{0,0,0,0},{0,0,0,0},{0,0,0,0}};
#pragma unroll
        for (int i = 0; i < 16; ++i) {
            const f4v v = *(const f4v*)(u2s + (r0 + i) * UP + 4 * fc);
#pragma unroll
            for (int j = 0; j < 4; ++j) {
                const int m = i - j;
                if (m >= 0 && m <= 12) c2[j] += K13[m] * v;
            }
        }
#pragma unroll
        for (int j = 0; j < 4; ++j)
            __builtin_nontemporal_store(c1[j] - c2[j],
                (f4v*)(op + 1 * HW + gbase + (size_t)j * 1024));

        // c3 = V3 u3 (29-tap): u3s rows [r0, r0+32)
        f4v c3[4] = {{0,0,0,0},{0,0,0,0},{0,0,0,0},{0,0,0,0}};
#pragma unroll
        for (int i = 0; i < 32; ++i) {
            const f4v v = *(const f4v*)(u3s + (r0 + i) * UP + 4 * fc);
#pragma unroll
            for (int j = 0; j < 4; ++j) {
                const int m = i - j;
                if (m >= 0 && m <= 28) c3[j] += K29[m] * v;
            }
        }
#pragma unroll
        for (int j = 0; j < 4; ++j) {
            __builtin_nontemporal_store(c2[j] - c3[j],
                (f4v*)(op + 2 * HW + gbase + (size_t)j * 1024));
            __builtin_nontemporal_store(c3[j],
                (f4v*)(op + 3 * HW + gbase + (size_t)j * 1024));
        }
    } else {
        // waves 4-5: w1 = x - c1 on 8-row strips
        const int lane = tid - 256;
        const int fc = lane & 15;
        const int r0 = (lane >> 4) * 8;

        f4v u1r[12];
#pragma unroll
        for (int i = 0; i < 12; ++i)
            u1r[i] = *(const f4v*)(u1s + (r0 + i) * UP + 4 * fc);
#pragma unroll
        for (int j = 0; j < 8; ++j) {
            const f4v c1 = 0.0625f * (u1r[j] + u1r[j + 4])
                         + 0.25f * (u1r[j + 1] + u1r[j + 3])
                         + 0.375f * u1r[j + 2];
            const size_t g = (size_t)(by + r0 + j) * 1024 + bx + 4 * fc;
            const f4v xc = *(const f4v*)(xp + g);
            __builtin_nontemporal_store(xc - c1, (f4v*)(op + 0 * HW + g));
        }
    }
}

extern "C" void kernel_launch(void* const* d_in, const int* in_sizes, int n_in,
                              void* d_out, int out_size, void* d_ws, size_t ws_size,
                              hipStream_t stream)
{
    const float* x = (const float*)d_in[0];
    float* out = (float*)d_out;
    uwt3_kernel<<<dim3(4096), dim3(TB), 0, stream>>>(x, out);
}